// Round 21
// baseline (229.440 us; speedup 1.0000x reference)
//
#include <hip/hip_runtime.h>
#include <hip/hip_bf16.h>
#include <hip/hip_fp16.h>

#define DD   1024
#define HH   16
#define DHH  64
#define SS   2048
#define BB   2

using f32x4 = __attribute__((ext_vector_type(4))) float;
using s16x8 = __attribute__((ext_vector_type(8))) short;
using s16x4 = __attribute__((ext_vector_type(4))) short;
using f16x8 = __attribute__((ext_vector_type(8))) _Float16;
using u32x4 = __attribute__((ext_vector_type(4))) unsigned;

#if __has_builtin(__builtin_amdgcn_exp2f)
#define EXP2(x) __builtin_amdgcn_exp2f(x)
#else
#define EXP2(x) exp2f(x)
#endif

// f32 -> fp16 bits (RNE)
static __device__ __forceinline__ short f2h(float x) {
    _Float16 h = (_Float16)x;
    return __builtin_bit_cast(short, h);
}
// packed f32x2 -> fp16x2 (RTZ, single instruction)
static __device__ __forceinline__ unsigned pk2(float a, float b) {
    auto h = __builtin_amdgcn_cvt_pkrtz(a, b);   // __fp16 ext_vector(2)
    return __builtin_bit_cast(unsigned, h);
}

// async 16B global->LDS (linear dest: wave-uniform base + lane*16)
static __device__ __forceinline__ void glds16(const void* g, void* l) {
    __builtin_amdgcn_global_load_lds(
        (const __attribute__((address_space(1))) unsigned int*)g,
        (__attribute__((address_space(3))) unsigned int*)l, 16, 0, 0);
}

// byte offset in a [rows][64 fp16] (=128B/row) LDS tile, XOR-swizzled 16B blocks
static __device__ __forceinline__ int swz(int row, int blk) {
    return row * 128 + (((blk) ^ (row & 7)) << 4);
}

static __device__ __forceinline__ f32x4 MFMA16(s16x8 a, s16x8 b, f32x4 c) {
    return __builtin_amdgcn_mfma_f32_16x16x32_f16(
        __builtin_bit_cast(f16x8, a), __builtin_bit_cast(f16x8, b), c, 0, 0, 0);
}

// Q pre-scale: (1/sqrt(64)) * log2(e), so attn can use exp2 directly
#define QSCALE 0.18033688011112042f

// ws byte offsets (fp16 everywhere)
#define WT_OFF 0u            /* Wt fp16 [3*16*64][1024]          6,291,456 B */
#define VT_OFF 6291456u      /* Vt3 fp16 frag layout             8,388,608 B */
#define QH_OFF 14680064u     /* Q fp16 [B,H,S,DH] (pre-scaled)   8,388,608 B */
#define KT_OFF 23068672u     /* Kt3 fp16 frag layout (permuted)  8,388,608 B */
#define XH_OFF 31457280u     /* X fp16 [B*S][D]                  8,388,608 B */

// ---------------------------------------------------------------------------
// K1: fused prep — blocks [0,2048): X->fp16 convert; [2048,2816): W->fp16
// transpose to Wt[mat*16+h][e][d].
// ---------------------------------------------------------------------------
__global__ __launch_bounds__(256) void prep_kernel(
    const float* __restrict__ X,
    const float* __restrict__ Wq, const float* __restrict__ Wk, const float* __restrict__ Wv,
    short* __restrict__ XhG, short* __restrict__ WtG)
{
    __shared__ float Ws[64][65];
    const int t = threadIdx.x;

    if (blockIdx.x < 2048) {
        size_t base = ((size_t)blockIdx.x * 256 + t) * 8;
        float4 a = *(const float4*)(X + base);
        float4 b = *(const float4*)(X + base + 4);
        s16x8 hv;
        hv[0] = f2h(a.x); hv[1] = f2h(a.y); hv[2] = f2h(a.z); hv[3] = f2h(a.w);
        hv[4] = f2h(b.x); hv[5] = f2h(b.y); hv[6] = f2h(b.z); hv[7] = f2h(b.w);
        *(s16x8*)(XhG + base) = hv;
        return;
    }

    const int bid = blockIdx.x - 2048;      // 0..767
    const int dt = bid & 15;                // d-tile (16)
    const int mh = bid >> 4;                // mat*16+h (48)
    const int mat = mh >> 4, h = mh & 15;
    const int d0 = dt * 64;
    const float* Wm = (mat == 0 ? Wq : (mat == 1 ? Wk : Wv)) + (size_t)h * DD * DHH;

#pragma unroll
    for (int i = 0; i < 4; i++) {
        int f = t + 256 * i;
        int row = f >> 4;          // d-local
        int c4  = f & 15;          // e quad
        float4 v = *(const float4*)(Wm + (size_t)(d0 + row) * DHH + c4 * 4);
        Ws[row][c4 * 4 + 0] = v.x;
        Ws[row][c4 * 4 + 1] = v.y;
        Ws[row][c4 * 4 + 2] = v.z;
        Ws[row][c4 * 4 + 3] = v.w;
    }
    __syncthreads();

    const int e = t >> 2, dq = t & 3;
    s16x8 h0, h1;
#pragma unroll
    for (int i = 0; i < 8; i++) h0[i] = f2h(Ws[dq * 16 + i][e]);
#pragma unroll
    for (int i = 0; i < 8; i++) h1[i] = f2h(Ws[dq * 16 + 8 + i][e]);
    size_t off = ((size_t)(mh * 64 + e)) * DD + d0 + dq * 16;
    *(s16x8*)(WtG + off)     = h0;
    *(s16x8*)(WtG + off + 8) = h1;
}

// ---------------------------------------------------------------------------
// K2: merged projection, branch-free inner loop. y in [0,16): Q/K (A=W, B=X);
// [16,24): V (A=X, B=W). Epilogues (cold): Q row-major scaled; K -> Kt3
// fragment layout with baked-in bit-permutation; V -> Vt3 fragment layout.
// ---------------------------------------------------------------------------
__global__ __launch_bounds__(256, 2) void proj_kernel(
    const short* __restrict__ XhG,
    const short* __restrict__ WtG,
    const float* __restrict__ bq, const float* __restrict__ bk,
    const float* __restrict__ bv,
    short* __restrict__ QhG, short* __restrict__ KtG, short* __restrict__ VtG)
{
    const int s0 = blockIdx.x * 128;
    const int y  = blockIdx.y;               // 0..23
    const bool isV = (y >= 16);
    const int n0 = isV ? (y - 16) * 128 : y * 128;
    const size_t wrow0 = (size_t)(isV ? 2048 + n0 : n0);   // row in Wt

    __shared__ __align__(16) char smem[32768];
    const int WT = 0, XT = 16384;

    const int t = threadIdx.x;
    const int w = t >> 6, lane = t & 63, g = lane >> 4, ln = lane & 15;
    const int wm = w >> 1, wn = w & 1;

    const char* Abase = smem + (isV ? XT : WT);
    const char* Bbase = smem + (isV ? WT : XT);

    f32x4 acc[4][4];
#pragma unroll
    for (int i = 0; i < 4; i++)
#pragma unroll
        for (int j = 0; j < 4; j++) acc[i][j] = (f32x4){0.f, 0.f, 0.f, 0.f};

    for (int d0 = 0; d0 < DD; d0 += 64) {
        if (d0) __syncthreads();
#pragma unroll
        for (int p = 0; p < 4; p++) {
            int idx = p * 256 + t;
            int row = idx >> 3, blk = idx & 7;
            int soff = (blk ^ (row & 7)) * 8;
            glds16(WtG + (wrow0 + row) * DD + d0 + soff, smem + WT + idx * 16);
            glds16(XhG + (size_t)(s0 + row) * DD + d0 + soff, smem + XT + idx * 16);
        }
        __syncthreads();

        s16x8 bfr[4][2];
#pragma unroll
        for (int nf = 0; nf < 4; nf++)
#pragma unroll
            for (int kst = 0; kst < 2; kst++)
                bfr[nf][kst] = *(const s16x8*)(Bbase + swz(64 * wn + nf * 16 + ln, kst * 4 + g));
#pragma unroll
        for (int mf = 0; mf < 4; mf++) {
            s16x8 afr[2];
#pragma unroll
            for (int kst = 0; kst < 2; kst++)
                afr[kst] = *(const s16x8*)(Abase + swz(64 * wm + mf * 16 + ln, kst * 4 + g));
#pragma unroll
            for (int kst = 0; kst < 2; kst++)
#pragma unroll
                for (int nf = 0; nf < 4; nf++)
                    acc[mf][nf] = MFMA16(afr[kst], bfr[nf][kst], acc[mf][nf]);
        }
    }

    if (!isV) {
        const int mat = n0 >> 10;                       // 0=Q, 1=K
        const int h = ((n0 + 64 * wm) >> 6) & 15;
        const float* bptr = (mat ? bk : bq) + h * 64;
#pragma unroll
        for (int nf = 0; nf < 4; nf++) {
            int sg = s0 + 64 * wn + nf * 16 + ln;
            int bidx = sg >> 11, sr = sg & (SS - 1);
            if (mat == 0) {
                // Q: row-major [B,H,S,DH], pre-scaled for exp2
                size_t rowbase = ((size_t)((bidx * HH + h) * SS + sr)) * DHH;
#pragma unroll
                for (int mf = 0; mf < 4; mf++) {
                    float4 bias = *(const float4*)(bptr + mf * 16 + g * 4);
                    float bb[4] = {bias.x, bias.y, bias.z, bias.w};
                    s16x4 h4;
#pragma unroll
                    for (int r = 0; r < 4; r++) h4[r] = f2h((acc[mf][nf][r] + bb[r]) * QSCALE);
                    *(s16x4*)(QhG + rowbase + mf * 16 + g * 4) = h4;
                }
            } else {
                // K -> Kt3: [kt][kst][mfa][ga][lna][8] with baked permutation
                size_t base = ((size_t)(bidx * HH + h)) * (SS * DHH);
                int kt2  = sr >> 6;
                int sr63 = sr & 63;
                int mfa = ((sr63 >> 5) & 1) * 2 + ((sr63 >> 2) & 1);
                int lna = ((sr63 >> 3) & 3) * 4 + (sr63 & 3);
#pragma unroll
                for (int mf = 0; mf < 4; mf++) {
                    float4 bias = *(const float4*)(bptr + mf * 16 + g * 4);
                    float bb[4] = {bias.x, bias.y, bias.z, bias.w};
                    s16x4 h4;
#pragma unroll
                    for (int r = 0; r < 4; r++) h4[r] = f2h(acc[mf][nf][r] + bb[r]);
                    int idx = (((((kt2 * 2 + (mf >> 1)) * 4 + mfa) * 4
                               + ((mf & 1) * 2 + (g >> 1))) * 16 + lna) << 3) + (g & 1) * 4;
                    *(s16x4*)(KtG + base + idx) = h4;
                }
            }
        }
    } else {
        // V epilogue: C row = s (A=X), col = e (B=W); write Vt3 frag layout
        const int h = ((n0 + 64 * wn) >> 6) & 15;
#pragma unroll
        for (int nf = 0; nf < 4; nf++) {
            int e = nf * 16 + ln;
            float bvv = bv[h * 64 + e];
#pragma unroll
            for (int mf = 0; mf < 4; mf++) {
                int sgb = s0 + 64 * wm + mf * 16 + g * 4;   // 4 consecutive s
                int bidx = sgb >> 11, sr = sgb & (SS - 1);
                s16x4 v4;
#pragma unroll
                for (int r = 0; r < 4; r++) v4[r] = f2h(acc[mf][nf][r] + bvv);
                size_t base = ((size_t)(bidx * HH + h)) * (SS * DHH);
                int idx = ((((((sr >> 6) * 2 + ((sr >> 5) & 1)) * 4 + nf) * 4
                            + ((sr >> 3) & 3)) * 16 + ln) << 3) + (sr & 7);
                *(s16x4*)(VtG + base + idx) = v4;
            }
        }
    }
}

// ---------------------------------------------------------------------------
// K3: attention — barrier-free + SOFTWARE-PIPELINED. No LDS, no barriers:
// K/V fragments from fragment-contiguous global layouts, with next tile's
// fragments loaded into "nxt" registers at the top of each iteration so the
// ~300cy L2 latency hides under the current tile's MFMA/exp chain (this was
// R20's missing piece). Kt3 bakes in the k-row bit-permutation -> P stays
// in registers in PV B-frag order. No online max; Q carries log2e -> exp2;
// unnormalized accumulate; row-sum once at end; pkrtz pack.
// ---------------------------------------------------------------------------
__global__ __launch_bounds__(256, 4) void attn_kernel(
    const short* __restrict__ QhG, const short* __restrict__ KtG,
    const short* __restrict__ VtG,
    float* __restrict__ out)
{
    // XCD swizzle: 1024 blocks, 8 XCDs, 128 wids/XCD contiguous
    const int wid = (blockIdx.x & 7) * 128 + (blockIdx.x >> 3);
    const int qraw = wid & 31, h = (wid >> 5) & 15, b = wid >> 9;
    const int qt = ((wid >> 5) & 1) ? (31 - qraw) : qraw;   // causal balance
    const int q0 = qt * 64;
    const size_t ho = (size_t)(b * HH + h) * SS * DHH;

    const int t = threadIdx.x;
    const int w = t >> 6, lane = t & 63, g = lane >> 4, ln = lane & 15;
    const int qrow = 16 * w + ln;            // 0..63
    const int qg = q0 + qrow;

    // Q fragments (read once, pre-scaled QSCALE)
    s16x8 qh[2];
#pragma unroll
    for (int kst = 0; kst < 2; kst++)
        qh[kst] = *(const s16x8*)(QhG + ho + (size_t)qg * DHH + kst * 32 + g * 8);

    f32x4 o[4];
#pragma unroll
    for (int i = 0; i < 4; i++) o[i] = (f32x4){0.f, 0.f, 0.f, 0.f};
    float lpart = 0.f;

    const int laneoff = (g * 16 + ln) * 8;   // shorts within a 1KB fragment
    const short* Kbase = KtG + ho + laneoff;
    const short* Vbase = VtG + ho + laneoff;

    // prologue: load tile 0
    s16x8 akc[4][2], avc[4][2], akn[4][2], avn[4][2];
#pragma unroll
    for (int mf = 0; mf < 4; mf++)
#pragma unroll
        for (int kst = 0; kst < 2; kst++) {
            akc[mf][kst] = *(const s16x8*)(Kbase + ((size_t)(kst * 4 + mf) << 9));
            avc[mf][kst] = *(const s16x8*)(Vbase + ((size_t)(kst * 4 + mf) << 9));
        }

    for (int kt = 0; kt < SS / 64; kt++) {
        const int k0 = kt * 64;
        const bool do_pv = (kt <= qt);

        // issue next tile's loads (latency hides under this tile's compute)
        if (kt + 1 < SS / 64) {
            const bool pv_n = (kt + 1 <= qt);
#pragma unroll
            for (int mf = 0; mf < 4; mf++)
#pragma unroll
                for (int kst = 0; kst < 2; kst++) {
                    size_t fo = (size_t)(((kt + 1) * 2 + kst) * 4 + mf) << 9;
                    akn[mf][kst] = *(const s16x8*)(Kbase + fo);
                    if (pv_n) avn[mf][kst] = *(const s16x8*)(Vbase + fo);
                }
        }

        // S^T tile: rows = permuted k, cols = q (16 per wave)
        f32x4 s[4];
#pragma unroll
        for (int i = 0; i < 4; i++) s[i] = (f32x4){0.f, 0.f, 0.f, 0.f};
#pragma unroll
        for (int kst = 0; kst < 2; kst++)
#pragma unroll
            for (int mf = 0; mf < 4; mf++)
                s[mf] = MFMA16(akc[mf][kst], qh[kst], s[mf]);

        // P = exp2(s); accumulate l partial
#pragma unroll
        for (int mf = 0; mf < 4; mf++)
#pragma unroll
            for (int r = 0; r < 4; r++)
                s[mf][r] = EXP2(s[mf][r]);
        {
            float p0 = (s[0][0] + s[0][1]) + (s[0][2] + s[0][3]);
            float p1 = (s[1][0] + s[1][1]) + (s[1][2] + s[1][3]);
            float p2 = (s[2][0] + s[2][1]) + (s[2][2] + s[2][3]);
            float p3 = (s[3][0] + s[3][1]) + (s[3][2] + s[3][3]);
            lpart += (p0 + p1) + (p2 + p3);
        }

        if (do_pv) {
            const bool diag = (kt == qt);
#pragma unroll
            for (int kst = 0; kst < 2; kst++) {
                u32x4 u;
                if (diag) {
                    int kb = k0 + kst * 32 + g * 8;
                    float pa[4], pb[4];
#pragma unroll
                    for (int r = 0; r < 4; r++) {
                        pa[r] = (kb + r     > qg) ? 0.f : s[2 * kst][r];
                        pb[r] = (kb + 4 + r > qg) ? 0.f : s[2 * kst + 1][r];
                    }
                    u.x = pk2(pa[0], pa[1]); u.y = pk2(pa[2], pa[3]);
                    u.z = pk2(pb[0], pb[1]); u.w = pk2(pb[2], pb[3]);
                } else {
                    u.x = pk2(s[2 * kst][0], s[2 * kst][1]);
                    u.y = pk2(s[2 * kst][2], s[2 * kst][3]);
                    u.z = pk2(s[2 * kst + 1][0], s[2 * kst + 1][1]);
                    u.w = pk2(s[2 * kst + 1][2], s[2 * kst + 1][3]);
                }
                s16x8 bp = __builtin_bit_cast(s16x8, u);
#pragma unroll
                for (int mf = 0; mf < 4; mf++)
                    o[mf] = MFMA16(avc[mf][kst], bp, o[mf]);
            }
        }

        // rotate pipeline registers
#pragma unroll
        for (int mf = 0; mf < 4; mf++)
#pragma unroll
            for (int kst = 0; kst < 2; kst++) {
                akc[mf][kst] = akn[mf][kst];
                avc[mf][kst] = avn[mf][kst];
            }
    }

    // final cross-lane row-sum (4 g-lanes share one q-row), then epilogue
    {
        float l = lpart;
        l += __shfl_xor(l, 16);
        l += __shfl_xor(l, 32);
        float inv = 1.0f / l;
        float* op = out + ((size_t)(b * SS + qg)) * (HH * DHH) + h * DHH;
#pragma unroll
        for (int mf = 0; mf < 4; mf++) {
            float4 vv = {o[mf][0] * inv, o[mf][1] * inv,
                         o[mf][2] * inv, o[mf][3] * inv};
            *(float4*)(op + mf * 16 + g * 4) = vv;
        }
    }
}

extern "C" void kernel_launch(void* const* d_in, const int* in_sizes, int n_in,
                              void* d_out, int out_size, void* d_ws, size_t ws_size,
                              hipStream_t stream) {
    const float* X  = (const float*)d_in[0];
    const float* Wq = (const float*)d_in[1];
    const float* Wk = (const float*)d_in[2];
    const float* Wv = (const float*)d_in[3];
    const float* bq = (const float*)d_in[4];
    const float* bk = (const float*)d_in[5];
    const float* bv = (const float*)d_in[6];
    float* out = (float*)d_out;

    char* wsb = (char*)d_ws;
    short* Wt = (short*)(wsb + WT_OFF);
    short* Vt = (short*)(wsb + VT_OFF);
    short* Qh = (short*)(wsb + QH_OFF);
    short* Kt = (short*)(wsb + KT_OFF);
    short* Xh = (short*)(wsb + XH_OFF);

    prep_kernel<<<2816, 256, 0, stream>>>(X, Wq, Wk, Wv, Xh, Wt);
    proj_kernel<<<dim3(32, 24), 256, 0, stream>>>(Xh, Wt, bq, bk, bv, Qh, Kt, Vt);
    attn_kernel<<<1024, 256, 0, stream>>>(Qh, Kt, Vt, out);
}

// Round 22
// 85.980 us; speedup vs baseline: 2.6685x; 2.6685x over previous
//
#include <hip/hip_runtime.h>
#include <hip/hip_bf16.h>
#include <hip/hip_fp16.h>

#define DD   1024
#define HH   16
#define DHH  64
#define SS   2048
#define BB   2

using f32x4 = __attribute__((ext_vector_type(4))) float;
using s16x8 = __attribute__((ext_vector_type(8))) short;
using s16x4 = __attribute__((ext_vector_type(4))) short;
using f16x8 = __attribute__((ext_vector_type(8))) _Float16;
using u32x4 = __attribute__((ext_vector_type(4))) unsigned;

#if __has_builtin(__builtin_amdgcn_exp2f)
#define EXP2(x) __builtin_amdgcn_exp2f(x)
#else
#define EXP2(x) exp2f(x)
#endif

// f32 -> fp16 bits (RNE)
static __device__ __forceinline__ short f2h(float x) {
    _Float16 h = (_Float16)x;
    return __builtin_bit_cast(short, h);
}
// packed f32x2 -> fp16x2 (RTZ, single instruction)
static __device__ __forceinline__ unsigned pk2(float a, float b) {
    auto h = __builtin_amdgcn_cvt_pkrtz(a, b);   // __fp16 ext_vector(2)
    return __builtin_bit_cast(unsigned, h);
}

// async 16B global->LDS (linear dest: wave-uniform base + lane*16)
static __device__ __forceinline__ void glds16(const void* g, void* l) {
    __builtin_amdgcn_global_load_lds(
        (const __attribute__((address_space(1))) unsigned int*)g,
        (__attribute__((address_space(3))) unsigned int*)l, 16, 0, 0);
}

// byte offset in a [rows][64 fp16] (=128B/row) LDS tile, XOR-swizzled 16B blocks
static __device__ __forceinline__ int swz(int row, int blk) {
    return row * 128 + (((blk) ^ (row & 7)) << 4);
}

static __device__ __forceinline__ f32x4 MFMA16(s16x8 a, s16x8 b, f32x4 c) {
    return __builtin_amdgcn_mfma_f32_16x16x32_f16(
        __builtin_bit_cast(f16x8, a), __builtin_bit_cast(f16x8, b), c, 0, 0, 0);
}

// Q pre-scale: (1/sqrt(64)) * log2(e), so attn can use exp2 directly
#define QSCALE 0.18033688011112042f

// ws byte offsets (fp16 everywhere)
#define WT_OFF 0u            /* Wt fp16 [3*16*64][1024]          6,291,456 B */
#define VT_OFF 6291456u      /* Vt3 fp16 frag layout             8,388,608 B */
#define QH_OFF 14680064u     /* Q fp16 [B,H,S,DH] (pre-scaled)   8,388,608 B */
#define KH_OFF 23068672u     /* K fp16 [B,H,S,DH]                8,388,608 B */
#define XH_OFF 31457280u     /* X fp16 [B*S][D]                  8,388,608 B */
/* total = 39,845,888 bytes */

// ---------------------------------------------------------------------------
// K1: fused prep — blocks [0,2048): X->fp16 convert; [2048,2816): W->fp16
// transpose to Wt[mat*16+h][e][d]. Top-level branch, both paths cold/simple.
// ---------------------------------------------------------------------------
__global__ __launch_bounds__(256) void prep_kernel(
    const float* __restrict__ X,
    const float* __restrict__ Wq, const float* __restrict__ Wk, const float* __restrict__ Wv,
    short* __restrict__ XhG, short* __restrict__ WtG)
{
    __shared__ float Ws[64][65];
    const int t = threadIdx.x;

    if (blockIdx.x < 2048) {
        size_t base = ((size_t)blockIdx.x * 256 + t) * 8;
        float4 a = *(const float4*)(X + base);
        float4 b = *(const float4*)(X + base + 4);
        s16x8 hv;
        hv[0] = f2h(a.x); hv[1] = f2h(a.y); hv[2] = f2h(a.z); hv[3] = f2h(a.w);
        hv[4] = f2h(b.x); hv[5] = f2h(b.y); hv[6] = f2h(b.z); hv[7] = f2h(b.w);
        *(s16x8*)(XhG + base) = hv;
        return;
    }

    const int bid = blockIdx.x - 2048;      // 0..767
    const int dt = bid & 15;                // d-tile (16)
    const int mh = bid >> 4;                // mat*16+h (48)
    const int mat = mh >> 4, h = mh & 15;
    const int d0 = dt * 64;
    const float* Wm = (mat == 0 ? Wq : (mat == 1 ? Wk : Wv)) + (size_t)h * DD * DHH;

#pragma unroll
    for (int i = 0; i < 4; i++) {
        int f = t + 256 * i;
        int row = f >> 4;          // d-local
        int c4  = f & 15;          // e quad
        float4 v = *(const float4*)(Wm + (size_t)(d0 + row) * DHH + c4 * 4);
        Ws[row][c4 * 4 + 0] = v.x;
        Ws[row][c4 * 4 + 1] = v.y;
        Ws[row][c4 * 4 + 2] = v.z;
        Ws[row][c4 * 4 + 3] = v.w;
    }
    __syncthreads();

    const int e = t >> 2, dq = t & 3;
    s16x8 h0, h1;
#pragma unroll
    for (int i = 0; i < 8; i++) h0[i] = f2h(Ws[dq * 16 + i][e]);
#pragma unroll
    for (int i = 0; i < 8; i++) h1[i] = f2h(Ws[dq * 16 + 8 + i][e]);
    size_t off = ((size_t)(mh * 64 + e)) * DD + d0 + dq * 16;
    *(s16x8*)(WtG + off)     = h0;
    *(s16x8*)(WtG + off + 8) = h1;
}

// ---------------------------------------------------------------------------
// K2: merged projection, BRANCH-FREE inner loop. blockIdx.y in [0,16): Q/K
// tile (A = W-LDS, B = X-LDS); [16,24): V tile (A = X-LDS, B = W-LDS).
// Operand roles chosen via wave-uniform LDS base pointers BEFORE the loop;
// staging identical; only the (cold) epilogue branches.
// ---------------------------------------------------------------------------
__global__ __launch_bounds__(256, 2) void proj_kernel(
    const short* __restrict__ XhG,
    const short* __restrict__ WtG,
    const float* __restrict__ bq, const float* __restrict__ bk,
    const float* __restrict__ bv,
    short* __restrict__ QhG, short* __restrict__ KhG, short* __restrict__ VtG)
{
    const int s0 = blockIdx.x * 128;
    const int y  = blockIdx.y;               // 0..23
    const bool isV = (y >= 16);
    const int n0 = isV ? (y - 16) * 128 : y * 128;
    const size_t wrow0 = (size_t)(isV ? 2048 + n0 : n0);   // row in Wt

    __shared__ __align__(16) char smem[32768];
    const int WT = 0, XT = 16384;

    const int t = threadIdx.x;
    const int w = t >> 6, lane = t & 63, g = lane >> 4, ln = lane & 15;
    const int wm = w >> 1, wn = w & 1;

    // operand-role selection (wave-uniform; no branch in loop)
    const char* Abase = smem + (isV ? XT : WT);
    const char* Bbase = smem + (isV ? WT : XT);

    f32x4 acc[4][4];
#pragma unroll
    for (int i = 0; i < 4; i++)
#pragma unroll
        for (int j = 0; j < 4; j++) acc[i][j] = (f32x4){0.f, 0.f, 0.f, 0.f};

    for (int d0 = 0; d0 < DD; d0 += 64) {
        if (d0) __syncthreads();
#pragma unroll
        for (int p = 0; p < 4; p++) {
            int idx = p * 256 + t;
            int row = idx >> 3, blk = idx & 7;
            int soff = (blk ^ (row & 7)) * 8;
            glds16(WtG + (wrow0 + row) * DD + d0 + soff, smem + WT + idx * 16);
            glds16(XhG + (size_t)(s0 + row) * DD + d0 + soff, smem + XT + idx * 16);
        }
        __syncthreads();

        s16x8 bfr[4][2];
#pragma unroll
        for (int nf = 0; nf < 4; nf++)
#pragma unroll
            for (int kst = 0; kst < 2; kst++)
                bfr[nf][kst] = *(const s16x8*)(Bbase + swz(64 * wn + nf * 16 + ln, kst * 4 + g));
#pragma unroll
        for (int mf = 0; mf < 4; mf++) {
            s16x8 afr[2];
#pragma unroll
            for (int kst = 0; kst < 2; kst++)
                afr[kst] = *(const s16x8*)(Abase + swz(64 * wm + mf * 16 + ln, kst * 4 + g));
#pragma unroll
            for (int kst = 0; kst < 2; kst++)
#pragma unroll
                for (int nf = 0; nf < 4; nf++)
                    acc[mf][nf] = MFMA16(afr[kst], bfr[nf][kst], acc[mf][nf]);
        }
    }

    if (!isV) {
        // Q/K epilogue: C row = n (A=W), col = s (B=X)
        const int mat = n0 >> 10;                       // 0=Q, 1=K
        const int h = ((n0 + 64 * wm) >> 6) & 15;
        const float* bptr = (mat ? bk : bq) + h * 64;
        short* OutP = mat ? KhG : QhG;
        const float scale = mat ? 1.0f : QSCALE;
#pragma unroll
        for (int nf = 0; nf < 4; nf++) {
            int sg = s0 + 64 * wn + nf * 16 + ln;
            int bidx = sg >> 11, sr = sg & (SS - 1);
            size_t rowbase = ((size_t)((bidx * HH + h) * SS + sr)) * DHH;
#pragma unroll
            for (int mf = 0; mf < 4; mf++) {
                float4 bias = *(const float4*)(bptr + mf * 16 + g * 4);
                float bb[4] = {bias.x, bias.y, bias.z, bias.w};
                s16x4 h4;
#pragma unroll
                for (int r = 0; r < 4; r++) h4[r] = f2h((acc[mf][nf][r] + bb[r]) * scale);
                *(s16x4*)(OutP + rowbase + mf * 16 + g * 4) = h4;
            }
        }
    } else {
        // V epilogue: C row = s (A=X), col = e (B=W); write Vt3 frag layout
        const int h = ((n0 + 64 * wn) >> 6) & 15;
#pragma unroll
        for (int nf = 0; nf < 4; nf++) {
            int e = nf * 16 + ln;
            float bvv = bv[h * 64 + e];
#pragma unroll
            for (int mf = 0; mf < 4; mf++) {
                int sgb = s0 + 64 * wm + mf * 16 + g * 4;   // 4 consecutive s
                int bidx = sgb >> 11, sr = sgb & (SS - 1);
                s16x4 v4;
#pragma unroll
                for (int r = 0; r < 4; r++) v4[r] = f2h(acc[mf][nf][r] + bvv);
                size_t base = ((size_t)(bidx * HH + h)) * (SS * DHH);
                int idx = ((((((sr >> 6) * 2 + ((sr >> 5) & 1)) * 4 + nf) * 4
                            + ((sr >> 3) & 3)) * 16 + ln) << 3) + (sr & 7);
                *(s16x4*)(VtG + base + idx) = v4;
            }
        }
    }
}

// ---------------------------------------------------------------------------
// K3: attention (best measured: 49.1-49.3 us). 64 q-rows/block, 4 waves,
// 1024 blocks (4/CU). K fp16 double-buffered at 128-row granularity (2x16KB),
// one barrier per 128 k; subtile loop not unrolled (no spills). Bit-permuted
// K rows -> P in registers; V frags from Vt3 (1KB contiguous). No online
// max; Q carries log2e -> exp2; unnormalized accumulate; row-sum at end.
// ---------------------------------------------------------------------------
__global__ __launch_bounds__(256, 4) void attn_kernel(
    const short* __restrict__ QhG, const short* __restrict__ KhG,
    const short* __restrict__ VtG,
    float* __restrict__ out)
{
    // XCD swizzle: 1024 blocks, 8 XCDs, 128 wids/XCD contiguous
    const int wid = (blockIdx.x & 7) * 128 + (blockIdx.x >> 3);
    const int qraw = wid & 31, h = (wid >> 5) & 15, b = wid >> 9;
    // causal-work balance: flip qt on alternate h
    const int qt = ((wid >> 5) & 1) ? (31 - qraw) : qraw;
    const int q0 = qt * 64;
    const size_t ho = (size_t)(b * HH + h) * SS * DHH;

    __shared__ __align__(16) char smem[32768];   // 2 bufs x 16KB (128 k-rows)

    const int t = threadIdx.x;
    const int w = t >> 6, lane = t & 63, g = lane >> 4, ln = lane & 15;
    const int qrow = 16 * w + ln;            // 0..63
    const int qg = q0 + qrow;

    // Q fragments straight from global (read once, pre-scaled QSCALE)
    s16x8 qh[2];
#pragma unroll
    for (int kst = 0; kst < 2; kst++)
        qh[kst] = *(const s16x8*)(QhG + ho + (size_t)qg * DHH + kst * 32 + g * 8);

    // K rows staged bit-permuted within each 64-row subtile:
    // lrow a holds krow(a)=a5*32+a3a2*8+a4*4+a1a0, so QK^T C-row (mf,g*4+r)
    // is k = (mf>>1)*32 + g*8 + (mf&1)*4 + r.
    int soffA[4], krowA[4];
#pragma unroll
    for (int p = 0; p < 4; p++) {
        int idx = p * 256 + t;
        int row = idx >> 3, blk = idx & 7;
        int lrow = row & 63, sub = row >> 6;
        soffA[p] = (blk ^ (lrow & 7)) * 8;
        krowA[p] = sub * 64
                 + ((lrow >> 5) & 1) * 32 + ((lrow >> 2) & 3) * 8
                 + ((lrow >> 4) & 1) * 4 + (lrow & 3);
    }

    auto stageK = [&](int buf, int it) {
        const int k0s = it * 128;
#pragma unroll
        for (int p = 0; p < 4; p++) {
            int idx = p * 256 + t;
            glds16(KhG + ho + (size_t)(k0s + krowA[p]) * DHH + soffA[p],
                   smem + buf * 16384 + idx * 16);
        }
    };

    stageK(0, 0);

    f32x4 o[4];
#pragma unroll
    for (int i = 0; i < 4; i++) o[i] = (f32x4){0.f, 0.f, 0.f, 0.f};
    float lpart = 0.f;     // per-lane partial of the full-row sum

    int cur = 0;
    for (int it = 0; it < SS / 128; it++) {
        __syncthreads();
        if (it < SS / 128 - 1) stageK(cur ^ 1, it + 1);
        const char* Kbase = smem + cur * 16384;

#pragma unroll 1
        for (int ss = 0; ss < 2; ss++) {
            const int kt2 = it * 2 + ss;
            const int k0 = kt2 * 64;
            const bool do_pv = (kt2 <= qt);

            // V fragments: 8 x 1KB-contiguous loads, consumed after exp
            s16x8 av[4][2];
            if (do_pv) {
#pragma unroll
                for (int mf = 0; mf < 4; mf++)
#pragma unroll
                    for (int kst = 0; kst < 2; kst++)
                        av[mf][kst] = *(const s16x8*)(VtG + ho +
                            ((((((size_t)kt2 * 2 + kst) * 4 + mf) * 4 + g) * 16 + ln) << 3));
            }

            // S^T subtile: rows = permuted k, cols = q (16 per wave)
            f32x4 s[4];
#pragma unroll
            for (int i = 0; i < 4; i++) s[i] = (f32x4){0.f, 0.f, 0.f, 0.f};

            const char* Kb = Kbase + ss * 8192;
#pragma unroll
            for (int kst = 0; kst < 2; kst++) {
                s16x8 ak[4];
#pragma unroll
                for (int mf = 0; mf < 4; mf++)
                    ak[mf] = *(const s16x8*)(Kb + swz(mf * 16 + ln, kst * 4 + g));
#pragma unroll
                for (int mf = 0; mf < 4; mf++)
                    s[mf] = MFMA16(ak[mf], qh[kst], s[mf]);
            }

            // P = exp2(s) directly (Q carries log2e); accumulate l partial
#pragma unroll
            for (int mf = 0; mf < 4; mf++)
#pragma unroll
                for (int r = 0; r < 4; r++)
                    s[mf][r] = EXP2(s[mf][r]);
            {
                float p0 = (s[0][0] + s[0][1]) + (s[0][2] + s[0][3]);
                float p1 = (s[1][0] + s[1][1]) + (s[1][2] + s[1][3]);
                float p2 = (s[2][0] + s[2][1]) + (s[2][2] + s[2][3]);
                float p3 = (s[3][0] + s[3][1]) + (s[3][2] + s[3][3]);
                lpart += (p0 + p1) + (p2 + p3);
            }

            if (do_pv) {
                const bool diag = (kt2 == qt);
#pragma unroll
                for (int kst = 0; kst < 2; kst++) {
                    // P lane-local in PV B-frag order: bp[j]=s[2*kst+(j>=4)][j&3]
                    u32x4 u;
                    if (diag) {
                        int kb = k0 + kst * 32 + g * 8;
                        float pa[4], pb[4];
#pragma unroll
                        for (int r = 0; r < 4; r++) {
                            pa[r] = (kb + r     > qg) ? 0.f : s[2 * kst][r];
                            pb[r] = (kb + 4 + r > qg) ? 0.f : s[2 * kst + 1][r];
                        }
                        u.x = pk2(pa[0], pa[1]); u.y = pk2(pa[2], pa[3]);
                        u.z = pk2(pb[0], pb[1]); u.w = pk2(pb[2], pb[3]);
                    } else {
                        u.x = pk2(s[2 * kst][0], s[2 * kst][1]);
                        u.y = pk2(s[2 * kst][2], s[2 * kst][3]);
                        u.z = pk2(s[2 * kst + 1][0], s[2 * kst + 1][1]);
                        u.w = pk2(s[2 * kst + 1][2], s[2 * kst + 1][3]);
                    }
                    s16x8 bp = __builtin_bit_cast(s16x8, u);
#pragma unroll
                    for (int mf = 0; mf < 4; mf++)
                        o[mf] = MFMA16(av[mf][kst], bp, o[mf]);
                }
            }
        }
        cur ^= 1;
    }

    // final cross-lane row-sum (4 g-lanes share one q-row), then epilogue
    {
        float l = lpart;
        l += __shfl_xor(l, 16);
        l += __shfl_xor(l, 32);
        float inv = 1.0f / l;
        float* op = out + ((size_t)(b * SS + qg)) * (HH * DHH) + h * DHH;
#pragma unroll
        for (int mf = 0; mf < 4; mf++) {
            float4 vv = {o[mf][0] * inv, o[mf][1] * inv,
                         o[mf][2] * inv, o[mf][3] * inv};
            *(float4*)(op + mf * 16 + g * 4) = vv;
        }
    }
}

extern "C" void kernel_launch(void* const* d_in, const int* in_sizes, int n_in,
                              void* d_out, int out_size, void* d_ws, size_t ws_size,
                              hipStream_t stream) {
    const float* X  = (const float*)d_in[0];
    const float* Wq = (const float*)d_in[1];
    const float* Wk = (const float*)d_in[2];
    const float* Wv = (const float*)d_in[3];
    const float* bq = (const float*)d_in[4];
    const float* bk = (const float*)d_in[5];
    const float* bv = (const float*)d_in[6];
    float* out = (float*)d_out;

    char* wsb = (char*)d_ws;
    short* Wt = (short*)(wsb + WT_OFF);
    short* Vt = (short*)(wsb + VT_OFF);
    short* Qh = (short*)(wsb + QH_OFF);
    short* Kh = (short*)(wsb + KH_OFF);
    short* Xh = (short*)(wsb + XH_OFF);

    prep_kernel<<<2816, 256, 0, stream>>>(X, Wq, Wk, Wv, Xh, Wt);
    proj_kernel<<<dim3(32, 24), 256, 0, stream>>>(Xh, Wt, bq, bk, bv, Qh, Kh, Vt);
    attn_kernel<<<1024, 256, 0, stream>>>(Qh, Kh, Vt, out);
}